// Round 9
// baseline (214.485 us; speedup 1.0000x reference)
//
#include <hip/hip_runtime.h>

#define D     512
#define NB1   256
#define NB2   512
#define LOG2E 1.44269504088896f

typedef unsigned int   uint_t;
typedef unsigned short ushort_t;
typedef float f2 __attribute__((ext_vector_type(2)));

struct alignas(16) F4 { f2 lo, hi; };

__device__ __forceinline__ float bflo(uint_t u) { return __uint_as_float(u << 16); }
__device__ __forceinline__ float bfhi(uint_t u) { return __uint_as_float(u & 0xffff0000u); }
__device__ __forceinline__ ushort_t f2bf(float f) {
    uint_t u = __float_as_uint(f);
    u += 0x7fffu + ((u >> 16) & 1u);   // RNE
    return (ushort_t)(u >> 16);
}

// packed helpers — compiler-generated v_pk_* (correct register alignment)
__device__ __forceinline__ f2 vfma(f2 a, f2 b, f2 c) { return __builtin_elementwise_fma(a, b, c); }
__device__ __forceinline__ f2 unplo(uint_t u0, uint_t u1) { f2 r; r.x = bflo(u0); r.y = bflo(u1); return r; }
__device__ __forceinline__ f2 unphi(uint_t u0, uint_t u1) { f2 r; r.x = bfhi(u0); r.y = bfhi(u1); return r; }

// DPP cross-lane float add helper (ctrl must be a literal)
#define DPPF(v, ctrl) __int_as_float(__builtin_amdgcn_update_dpp(0, __float_as_int(v), ctrl, 0xf, 0xf, true))

// ================= merged prep kernel =================
__global__ __launch_bounds__(256) void prep_kernel(
    const float* __restrict__ emb1, const float* __restrict__ emb2,
    const float* __restrict__ cert2, const float* __restrict__ links,
    float* __restrict__ n1, ushort_t* __restrict__ n2h, ushort_t* __restrict__ c2h,
    uint_t* __restrict__ pidx, float* __restrict__ wval)
{
    const int blk  = blockIdx.x;
    const int lane = threadIdx.x & 63;
    const int w    = threadIdx.x >> 6;

    if (blk < 192) {                       // ---- normalize emb1 -> f32
        int row = blk * 4 + w;
        const float* r = emb1 + (size_t)row * D;
        float v[8]; float s = 0.f;
#pragma unroll
        for (int i = 0; i < 8; ++i) { v[i] = r[i * 64 + lane]; s += v[i] * v[i]; }
#pragma unroll
        for (int off = 32; off; off >>= 1) s += __shfl_xor(s, off);
        float inv = 1.f / fmaxf(sqrtf(s), 1e-12f);
        float* o = n1 + (size_t)row * D;
#pragma unroll
        for (int i = 0; i < 8; ++i) o[i * 64 + lane] = v[i] * inv;
    } else if (blk < 576) {                // ---- normalize emb2 -> bf16
        int row = (blk - 192) * 4 + w;
        const float* r = emb2 + (size_t)row * D;
        float v[8]; float s = 0.f;
#pragma unroll
        for (int i = 0; i < 8; ++i) { v[i] = r[i * 64 + lane]; s += v[i] * v[i]; }
#pragma unroll
        for (int off = 32; off; off >>= 1) s += __shfl_xor(s, off);
        float inv = 1.f / fmaxf(sqrtf(s), 1e-12f);
        ushort_t* o = n2h + (size_t)row * D;
#pragma unroll
        for (int i = 0; i < 8; ++i) o[i * 64 + lane] = f2bf(v[i] * inv);
    } else if (blk < 1088) {               // ---- cert2 layers 1,2 -> bf16
        int t = (blk - 576) * 256 + threadIdx.x;
        const float* s4 = cert2 + (size_t)NB2 * D + (size_t)t * 4;
        float4 v = *(const float4*)s4;
        uint2 o;
        o.x = (uint_t)f2bf(v.x) | ((uint_t)f2bf(v.y) << 16);
        o.y = (uint_t)f2bf(v.z) | ((uint_t)f2bf(v.w) << 16);
        *(uint2*)(c2h + (size_t)t * 4) = o;
    } else {                               // ---- top-3 per column
        int gw = (blk - 1088) * 4 + w;     // l*512 + e
        int l = gw >> 9;
        int e = gw & (D - 1);
        const float* base = links + (size_t)l * D * D + e;
        float v[8];
#pragma unroll
        for (int i = 0; i < 8; ++i) v[i] = base[(size_t)(i * 64 + lane) * D];
        float mv[3]; int mi[3];
        for (int k = 0; k < 3; ++k) {
            float lm = -1.f; int li = 0x7fffffff;
#pragma unroll
            for (int i = 0; i < 8; ++i)
                if (v[i] > lm) { lm = v[i]; li = i * 64 + lane; }
#pragma unroll
            for (int off = 32; off; off >>= 1) {
                float ov = __shfl_xor(lm, off);
                int oi = __shfl_xor(li, off);
                if (ov > lm || (ov == lm && oi < li)) { lm = ov; li = oi; }
            }
            mv[k] = lm; mi[k] = li;
            if (li < D && (li & 63) == lane) v[li >> 6] = -1.f;
        }
        if (lane == 0) {
            float invs = 1.f / (mv[0] + mv[1] + mv[2] + 1e-8f);
            uint_t f0 = (uint_t)mi[0] ^ (((uint_t)mi[0] >> 3) & 7u);
            uint_t f1 = (uint_t)mi[1] ^ (((uint_t)mi[1] >> 3) & 7u);
            uint_t f2m = (uint_t)mi[2] ^ (((uint_t)mi[2] >> 3) & 7u);
            pidx[gw] = f0 | (f1 << 9) | (f2m << 18);
            wval[(l * 3 + 0) * D + e] = mv[0] * invs;
            wval[(l * 3 + 1) * D + e] = mv[1] * invs;
            wval[(l * 3 + 2) * D + e] = mv[2] * invs;
        }
    }
}

// ================= gather-triple bank balance (8-lane-cluster model) =================
// LDS serves 128B/cycle = 8 lanes of b128 per cycle: conflicts are per 8-lane
// cluster. Greedy: per cluster, pick the triple-permutation so each gather
// position's 8 slots hit distinct bank-groups; 64-lane packed counters break ties.
__global__ __launch_bounds__(256) void balance_kernel(uint_t* __restrict__ pidx,
                                                      float* __restrict__ wval) {
    __shared__ uint_t sp[2 * D];          // 4 KB
    __shared__ float  sw[6 * D];          // 12 KB
    const int tid = threadIdx.x;

    {
        uint4 v = *(const uint4*)(pidx + tid * 4);
        *(uint4*)(sp + tid * 4) = v;
#pragma unroll
        for (int k = 0; k < 3; ++k) {
            float4 f = *(const float4*)(wval + k * 1024 + tid * 4);
            *(float4*)(sw + k * 1024 + tid * 4) = f;
        }
    }
    __syncthreads();

    if (tid < 16) {
        const int l   = tid >> 3;
        const int w   = (tid >> 1) & 3;
        const int par = tid & 1;
        uint_t m0 = 0, m1 = 0, m2 = 0;                     // per-cluster group masks
        unsigned long long cnt0 = 0, cnt1 = 0, cnt2 = 0;   // 64-lane packed counters
        for (int j = 0; j < 64; ++j) {
            if (!(j & 7)) { m0 = 0; m1 = 0; m2 = 0; }
            int e = w * 128 + par + j * 2;
            uint_t p = sp[l * D + e];
            uint_t sA = p & 511u, sB = (p >> 9) & 511u, sC = (p >> 18) & 511u;
            float wA = sw[(l*3+0)*D+e], wB = sw[(l*3+1)*D+e], wC = sw[(l*3+2)*D+e];
            uint_t b0 = sA, b1 = sB, b2 = sC;
            float  q0 = wA, q1 = wB, q2 = wC;
            int bc = 0x7fffffff;
#define TRY(x0,x1,x2,y0,y1,y2) { \
    int mc = (int)((m0 >> ((x0) & 7u)) & 1u) + (int)((m1 >> ((x1) & 7u)) & 1u) + \
             (int)((m2 >> ((x2) & 7u)) & 1u); \
    int cc = (int)((cnt0 >> (((x0) & 7u) * 8)) & 0xffu) + \
             (int)((cnt1 >> (((x1) & 7u) * 8)) & 0xffu) + \
             (int)((cnt2 >> (((x2) & 7u) * 8)) & 0xffu); \
    int c = mc * 1024 + cc; \
    if (c < bc) { bc = c; b0 = x0; b1 = x1; b2 = x2; q0 = y0; q1 = y1; q2 = y2; } }
            TRY(sA, sB, sC, wA, wB, wC)
            TRY(sA, sC, sB, wA, wC, wB)
            TRY(sB, sA, sC, wB, wA, wC)
            TRY(sB, sC, sA, wB, wC, wA)
            TRY(sC, sA, sB, wC, wA, wB)
            TRY(sC, sB, sA, wC, wB, wA)
#undef TRY
            m0 |= 1u << (b0 & 7u); m1 |= 1u << (b1 & 7u); m2 |= 1u << (b2 & 7u);
            cnt0 += 1ull << ((b0 & 7u) * 8);
            cnt1 += 1ull << ((b1 & 7u) * 8);
            cnt2 += 1ull << ((b2 & 7u) * 8);
            sp[l * D + e] = b0 | (b1 << 9) | (b2 << 18);
            sw[(l*3+0)*D+e] = q0;
            sw[(l*3+1)*D+e] = q1;
            sw[(l*3+2)*D+e] = q2;
        }
    }
    __syncthreads();

    {
        uint4 v = *(const uint4*)(sp + tid * 4);
        *(uint4*)(pidx + tid * 4) = v;
#pragma unroll
        for (int k = 0; k < 3; ++k) {
            float4 f = *(const float4*)(sw + k * 1024 + tid * 4);
            *(float4*)(wval + k * 1024 + tid * 4) = f;
        }
    }
}

// ---- fused rectify blend for one e-half, one nn-pair (packed over nn)
__device__ __forceinline__ f2 blend(f2 gA, f2 gB, f2 gC, f2 w0, f2 w1, f2 w2,
                                    f2 acn, f2 btn, f2 cc, f2 rr, f2 aa, f2 one2) {
    f2 gs = vfma(w0, gA, vfma(w1, gB, w2 * gC));
    f2 t  = vfma(acn, cc, btn);
    f2 E; E.x = __builtin_amdgcn_exp2f(t.x); E.y = __builtin_amdgcn_exp2f(t.y);
    f2 A  = E + one2;
    f2 P; P.x = __builtin_amdgcn_rcpf(A.x); P.y = __builtin_amdgcn_rcpf(A.y);
    f2 d  = aa - rr;
    f2 q  = one2 - P;
    f2 nd = d * d;
    return vfma(gs, q, P * nd);            // gs*(1-P) + P*node
}

// ================= fused main kernel =================
__global__ __launch_bounds__(256, 6) void avsl_main_kernel(
    const float* __restrict__ n1,      // (3,B1,D) f32 normalized emb1
    const ushort_t* __restrict__ n2h,  // (3,B2,D) bf16 normalized emb2
    const float* __restrict__ cert1,   // (3,B1,D) f32
    const ushort_t* __restrict__ c2h,  // (2,B2,D) bf16 cert2 layers 1,2
    const uint_t* __restrict__ pidx,   // (2,D) phi-swizzled, cluster-balanced indices
    const float* __restrict__ wval,    // (2,3,D) matched weights
    const float* __restrict__ alpha,   // (2,D)
    const float* __restrict__ beta,    // (2,D)
    float* __restrict__ out)           // (B1,B2)
{
    __shared__ F4 vbuf[3 * D];         // v0 ping / v0 pong / v1
    __shared__ float pbuf[16];
    const int tid  = threadIdx.x;
    const int lane = tid & 63;
    const int wid  = tid >> 6;
    const int b    = blockIdx.x >> 4;
    const int n0   = (blockIdx.x & 15) * 32;
    const int e0   = wid * 128 + lane * 2;     // lane owns e0, e0+1

    // ---- persistent per-e tables (scalars duplicated into f2 halves for pk ops)
    float2 a0  = *(const float2*)(n1 + (size_t)(0 * NB1 + b) * D + e0);
    float2 a1  = *(const float2*)(n1 + (size_t)(1 * NB1 + b) * D + e0);
    float2 a2  = *(const float2*)(n1 + (size_t)(2 * NB1 + b) * D + e0);
    float2 al1 = *(const float2*)(alpha + e0);
    float2 al2 = *(const float2*)(alpha + D + e0);
    float2 c11 = *(const float2*)(cert1 + (size_t)(1 * NB1 + b) * D + e0);
    float2 c12 = *(const float2*)(cert1 + (size_t)(2 * NB1 + b) * D + e0);
    float2 be1 = *(const float2*)(beta + e0);
    float2 be2 = *(const float2*)(beta + D + e0);

    const f2 one2 = { 1.f, 1.f };
    f2 a0xx = { a0.x, a0.x }, a0yy = { a0.y, a0.y };
    f2 a1xx = { a1.x, a1.x }, a1yy = { a1.y, a1.y };
    f2 a2xx = { a2.x, a2.x }, a2yy = { a2.y, a2.y };
    f2 acn1xx = { -al1.x * c11.x * LOG2E, -al1.x * c11.x * LOG2E };
    f2 acn1yy = { -al1.y * c11.y * LOG2E, -al1.y * c11.y * LOG2E };
    f2 acn2xx = { -al2.x * c12.x * LOG2E, -al2.x * c12.x * LOG2E };
    f2 acn2yy = { -al2.y * c12.y * LOG2E, -al2.y * c12.y * LOG2E };
    f2 btn1xx = { -be1.x * LOG2E, -be1.x * LOG2E };
    f2 btn1yy = { -be1.y * LOG2E, -be1.y * LOG2E };
    f2 btn2xx = { -be2.x * LOG2E, -be2.x * LOG2E };
    f2 btn2yy = { -be2.y * LOG2E, -be2.y * LOG2E };

    f2 w1x[3], w1y[3], w2x[3], w2y[3];
#pragma unroll
    for (int k = 0; k < 3; ++k) {
        float2 t1 = *(const float2*)(wval + k * D + e0);
        float2 t2 = *(const float2*)(wval + (3 + k) * D + e0);
        w1x[k].x = t1.x; w1x[k].y = t1.x;
        w1y[k].x = t1.y; w1y[k].y = t1.y;
        w2x[k].x = t2.x; w2x[k].y = t2.x;
        w2y[k].x = t2.y; w2y[k].y = t2.y;
    }
    uint2 p1 = *(const uint2*)(pidx + e0);
    uint2 p2 = *(const uint2*)(pidx + D + e0);

    // hoisted LDS gather pointers (parity handled via [512] imm offset)
    const F4* q1a0 = &vbuf[p1.x & 511u];
    const F4* q1b0 = &vbuf[(p1.x >> 9) & 511u];
    const F4* q1c0 = &vbuf[(p1.x >> 18) & 511u];
    const F4* q1a1 = &vbuf[p1.y & 511u];
    const F4* q1b1 = &vbuf[(p1.y >> 9) & 511u];
    const F4* q1c1 = &vbuf[(p1.y >> 18) & 511u];
    const F4* q2a0 = &vbuf[1024 + (p2.x & 511u)];
    const F4* q2b0 = &vbuf[1024 + ((p2.x >> 9) & 511u)];
    const F4* q2c0 = &vbuf[1024 + ((p2.x >> 18) & 511u)];
    const F4* q2a1 = &vbuf[1024 + (p2.y & 511u)];
    const F4* q2b1 = &vbuf[1024 + ((p2.y >> 9) & 511u)];
    const F4* q2c1 = &vbuf[1024 + ((p2.y >> 18) & 511u)];
    const int sl0 = e0 ^ ((e0 >> 3) & 7);
    const int sl1 = (e0 + 1) ^ (((e0 + 1) >> 3) & 7);
    F4* qw0a = &vbuf[sl0];
    F4* qw0b = &vbuf[sl1];
    F4* qw1a = &vbuf[1024 + sl0];
    F4* qw1b = &vbuf[1024 + sl1];

    // stream pointers (advanced 4 rows per group)
    const ushort_t* pr0 = n2h + (size_t)(0 * NB2 + n0) * D + e0;
    const ushort_t* pr1 = n2h + (size_t)(1 * NB2 + n0) * D + e0;
    const ushort_t* pr2 = n2h + (size_t)(2 * NB2 + n0) * D + e0;
    const ushort_t* pc1 = c2h + (size_t)(0 * NB2 + n0) * D + e0;
    const ushort_t* pc2 = c2h + (size_t)(1 * NB2 + n0) * D + e0;

    // ---- prologue: loads for g=0, L0(0) -> v0[ping]
    uint_t r1c[4], c1c[4], r0c[4];
#pragma unroll
    for (int nn = 0; nn < 4; ++nn) {
        r0c[nn] = *(const uint_t*)(pr0 + nn * D);
        r1c[nn] = *(const uint_t*)(pr1 + nn * D);
        c1c[nn] = *(const uint_t*)(pc1 + nn * D);
    }
    {
        F4 v0a, v0b; f2 d;
        d = a0xx - unplo(r0c[0], r0c[1]); v0a.lo = d * d;
        d = a0xx - unplo(r0c[2], r0c[3]); v0a.hi = d * d;
        d = a0yy - unphi(r0c[0], r0c[1]); v0b.lo = d * d;
        d = a0yy - unphi(r0c[2], r0c[3]); v0b.hi = d * d;
        qw0a[0] = v0a;
        qw0b[0] = v0b;
    }
    __syncthreads();

#pragma unroll 2
    for (int g = 0; g < 8; ++g) {
        // ================= phase A =================
        if (g) {
            if (tid < 4)
                out[(size_t)b * NB2 + n0 + (g - 1) * 4 + tid] =
                    pbuf[tid] + pbuf[4 + tid] + pbuf[8 + tid] + pbuf[12 + tid];
        }
        uint_t r0n[4], r2c[4], c2c[4];
#pragma unroll
        for (int nn = 0; nn < 4; ++nn) {
            r0n[nn] = *(const uint_t*)(pr0 + (4 + nn) * D);
            r2c[nn] = *(const uint_t*)(pr2 + nn * D);
            c2c[nn] = *(const uint_t*)(pc2 + nn * D);
        }
        // L1: gather v0[g&1], blend, write v1
        {
            F4 gA0 = q1a0[(g & 1) * 512], gB0 = q1b0[(g & 1) * 512], gC0 = q1c0[(g & 1) * 512];
            F4 gA1 = q1a1[(g & 1) * 512], gB1 = q1b1[(g & 1) * 512], gC1 = q1c1[(g & 1) * 512];
            f2 r1xa = unplo(r1c[0], r1c[1]), r1xb = unplo(r1c[2], r1c[3]);
            f2 r1ya = unphi(r1c[0], r1c[1]), r1yb = unphi(r1c[2], r1c[3]);
            f2 c1xa = unplo(c1c[0], c1c[1]), c1xb = unplo(c1c[2], c1c[3]);
            f2 c1ya = unphi(c1c[0], c1c[1]), c1yb = unphi(c1c[2], c1c[3]);
            F4 o0, o1;
            o0.lo = blend(gA0.lo, gB0.lo, gC0.lo, w1x[0], w1x[1], w1x[2],
                          acn1xx, btn1xx, c1xa, r1xa, a1xx, one2);
            o0.hi = blend(gA0.hi, gB0.hi, gC0.hi, w1x[0], w1x[1], w1x[2],
                          acn1xx, btn1xx, c1xb, r1xb, a1xx, one2);
            o1.lo = blend(gA1.lo, gB1.lo, gC1.lo, w1y[0], w1y[1], w1y[2],
                          acn1yy, btn1yy, c1ya, r1ya, a1yy, one2);
            o1.hi = blend(gA1.hi, gB1.hi, gC1.hi, w1y[0], w1y[1], w1y[2],
                          acn1yy, btn1yy, c1yb, r1yb, a1yy, one2);
            qw1a[0] = o0;
            qw1b[0] = o1;
        }
        __syncthreads();

        // ================= phase B =================
        uint_t r1n[4], c1n[4];
#pragma unroll
        for (int nn = 0; nn < 4; ++nn) {
            r1n[nn] = *(const uint_t*)(pr1 + (4 + nn) * D);
            c1n[nn] = *(const uint_t*)(pc1 + (4 + nn) * D);
        }
        // L2: gather v1, blend, accumulate
        f2 acc_a, acc_b;
        {
            F4 gA0 = q2a0[0], gB0 = q2b0[0], gC0 = q2c0[0];
            F4 gA1 = q2a1[0], gB1 = q2b1[0], gC1 = q2c1[0];
            f2 r2xa = unplo(r2c[0], r2c[1]), r2xb = unplo(r2c[2], r2c[3]);
            f2 r2ya = unphi(r2c[0], r2c[1]), r2yb = unphi(r2c[2], r2c[3]);
            f2 c2xa = unplo(c2c[0], c2c[1]), c2xb = unplo(c2c[2], c2c[3]);
            f2 c2ya = unphi(c2c[0], c2c[1]), c2yb = unphi(c2c[2], c2c[3]);
            acc_a = blend(gA0.lo, gB0.lo, gC0.lo, w2x[0], w2x[1], w2x[2],
                          acn2xx, btn2xx, c2xa, r2xa, a2xx, one2);
            acc_b = blend(gA0.hi, gB0.hi, gC0.hi, w2x[0], w2x[1], w2x[2],
                          acn2xx, btn2xx, c2xb, r2xb, a2xx, one2);
            acc_a = acc_a + blend(gA1.lo, gB1.lo, gC1.lo, w2y[0], w2y[1], w2y[2],
                                  acn2yy, btn2yy, c2ya, r2ya, a2yy, one2);
            acc_b = acc_b + blend(gA1.hi, gB1.hi, gC1.hi, w2y[0], w2y[1], w2y[2],
                                  acn2yy, btn2yy, c2yb, r2yb, a2yy, one2);
        }
        // L0 for g+1 -> v0[(g+1)&1]
        {
            F4 v0a, v0b; f2 d;
            d = a0xx - unplo(r0n[0], r0n[1]); v0a.lo = d * d;
            d = a0xx - unplo(r0n[2], r0n[3]); v0a.hi = d * d;
            d = a0yy - unphi(r0n[0], r0n[1]); v0b.lo = d * d;
            d = a0yy - unphi(r0n[2], r0n[3]); v0b.hi = d * d;
            qw0a[((g + 1) & 1) * 512] = v0a;
            qw0b[((g + 1) & 1) * 512] = v0b;
        }
        // wave reduction: DPP split butterfly (VALU) + xor16 swizzle + xor32
        {
            float c0 = acc_a.x, c1 = acc_a.y, c2 = acc_b.x, c3 = acc_b.y;
            float pA = DPPF(c0, 0xB1);   // quad_perm [1,0,3,2]  (xor 1)
            float pB = DPPF(c1, 0xB1);
            float pC = DPPF(c2, 0xB1);
            float pD = DPPF(c3, 0xB1);
            float u0, u1;
            if (lane & 1) { u0 = c1 + pB; u1 = c3 + pD; }
            else          { u0 = c0 + pA; u1 = c2 + pC; }
            float q0 = DPPF(u0, 0x4E);   // quad_perm [2,3,0,1]  (xor 2)
            float q1 = DPPF(u1, 0x4E);
            float v = (lane & 2) ? (u1 + q1) : (u0 + q0);   // holds nn = lane&3
            v += DPPF(v, 0x124);          // row_ror:4
            v += DPPF(v, 0x128);          // row_ror:8
            v += __int_as_float(__builtin_amdgcn_ds_swizzle(__float_as_int(v), 0x401F)); // xor 16
            v += __shfl_xor(v, 32);
            if (lane < 4) pbuf[wid * 4 + lane] = v;
        }
        __syncthreads();

#pragma unroll
        for (int nn = 0; nn < 4; ++nn) { r1c[nn] = r1n[nn]; c1c[nn] = c1n[nn]; }
        pr0 += 4 * D; pr1 += 4 * D; pr2 += 4 * D; pc1 += 4 * D; pc2 += 4 * D;
    }

    // epilogue: out-write for g=7
    if (tid < 4)
        out[(size_t)b * NB2 + n0 + 28 + tid] =
            pbuf[tid] + pbuf[4 + tid] + pbuf[8 + tid] + pbuf[12 + tid];
}

extern "C" void kernel_launch(void* const* d_in, const int* in_sizes, int n_in,
                              void* d_out, int out_size, void* d_ws, size_t ws_size,
                              hipStream_t stream) {
    const float* emb1  = (const float*)d_in[0];  // (3,256,512)
    const float* cert1 = (const float*)d_in[1];  // (3,256,512)
    const float* emb2  = (const float*)d_in[2];  // (3,512,512)
    const float* cert2 = (const float*)d_in[3];  // (3,512,512)
    const float* links = (const float*)d_in[4];  // (2,512,512)
    const float* alpha = (const float*)d_in[5];  // (2,512)
    const float* beta  = (const float*)d_in[6];  // (2,512)
    float* out = (float*)d_out;                  // (256,512)

    float* n1      = (float*)d_ws;                      // 3*256*512 f32
    ushort_t* n2h  = (ushort_t*)(n1 + 3 * NB1 * D);     // 3*512*512 bf16
    ushort_t* c2h  = n2h + 3 * NB2 * D;                 // 2*512*512 bf16
    uint_t* pidx   = (uint_t*)(c2h + 2 * NB2 * D);      // 2*512 u32
    float* wval    = (float*)(pidx + 2 * D);            // 2*3*512 f32

    hipLaunchKernelGGL(prep_kernel, dim3(1344), dim3(256), 0, stream,
                       emb1, emb2, cert2, links, n1, n2h, c2h, pidx, wval);
    hipLaunchKernelGGL(balance_kernel, dim3(1), dim3(256), 0, stream, pidx, wval);
    hipLaunchKernelGGL(avsl_main_kernel, dim3(4096), dim3(256), 0, stream,
                       n1, n2h, cert1, c2h, pidx, wval, alpha, beta, out);
}

// Round 10
// 80.928 us; speedup vs baseline: 2.6503x; 2.6503x over previous
//
#include <hip/hip_runtime.h>

#define D     512
#define NB1   256
#define NB2   512
#define LOG2E 1.44269504088896f

typedef unsigned int   uint_t;
typedef unsigned short ushort_t;
typedef float f2 __attribute__((ext_vector_type(2)));

struct alignas(16) F4 { f2 lo, hi; };

__device__ __forceinline__ float bflo(uint_t u) { return __uint_as_float(u << 16); }
__device__ __forceinline__ float bfhi(uint_t u) { return __uint_as_float(u & 0xffff0000u); }
__device__ __forceinline__ ushort_t f2bf(float f) {
    uint_t u = __float_as_uint(f);
    u += 0x7fffu + ((u >> 16) & 1u);   // RNE
    return (ushort_t)(u >> 16);
}

// packed helpers — compiler-generated v_pk_* (correct register alignment)
__device__ __forceinline__ f2 vfma(f2 a, f2 b, f2 c) { return __builtin_elementwise_fma(a, b, c); }
__device__ __forceinline__ f2 unplo(uint_t u0, uint_t u1) { f2 r; r.x = bflo(u0); r.y = bflo(u1); return r; }
__device__ __forceinline__ f2 unphi(uint_t u0, uint_t u1) { f2 r; r.x = bfhi(u0); r.y = bfhi(u1); return r; }

// DPP cross-lane float add helper (ctrl must be a literal)
#define DPPF(v, ctrl) __int_as_float(__builtin_amdgcn_update_dpp(0, __float_as_int(v), ctrl, 0xf, 0xf, true))

// ================= merged prep kernel =================
__global__ __launch_bounds__(256) void prep_kernel(
    const float* __restrict__ emb1, const float* __restrict__ emb2,
    const float* __restrict__ cert2, const float* __restrict__ links,
    float* __restrict__ n1, ushort_t* __restrict__ n2h, ushort_t* __restrict__ c2h,
    uint_t* __restrict__ pidx, float* __restrict__ wval)
{
    const int blk  = blockIdx.x;
    const int lane = threadIdx.x & 63;
    const int w    = threadIdx.x >> 6;

    if (blk < 192) {                       // ---- normalize emb1 -> f32
        int row = blk * 4 + w;
        const float* r = emb1 + (size_t)row * D;
        float v[8]; float s = 0.f;
#pragma unroll
        for (int i = 0; i < 8; ++i) { v[i] = r[i * 64 + lane]; s += v[i] * v[i]; }
#pragma unroll
        for (int off = 32; off; off >>= 1) s += __shfl_xor(s, off);
        float inv = 1.f / fmaxf(sqrtf(s), 1e-12f);
        float* o = n1 + (size_t)row * D;
#pragma unroll
        for (int i = 0; i < 8; ++i) o[i * 64 + lane] = v[i] * inv;
    } else if (blk < 576) {                // ---- normalize emb2 -> bf16
        int row = (blk - 192) * 4 + w;
        const float* r = emb2 + (size_t)row * D;
        float v[8]; float s = 0.f;
#pragma unroll
        for (int i = 0; i < 8; ++i) { v[i] = r[i * 64 + lane]; s += v[i] * v[i]; }
#pragma unroll
        for (int off = 32; off; off >>= 1) s += __shfl_xor(s, off);
        float inv = 1.f / fmaxf(sqrtf(s), 1e-12f);
        ushort_t* o = n2h + (size_t)row * D;
#pragma unroll
        for (int i = 0; i < 8; ++i) o[i * 64 + lane] = f2bf(v[i] * inv);
    } else if (blk < 1088) {               // ---- cert2 layers 1,2 -> bf16
        int t = (blk - 576) * 256 + threadIdx.x;
        const float* s4 = cert2 + (size_t)NB2 * D + (size_t)t * 4;
        float4 v = *(const float4*)s4;
        uint2 o;
        o.x = (uint_t)f2bf(v.x) | ((uint_t)f2bf(v.y) << 16);
        o.y = (uint_t)f2bf(v.z) | ((uint_t)f2bf(v.w) << 16);
        *(uint2*)(c2h + (size_t)t * 4) = o;
    } else {                               // ---- top-3 per column
        int gw = (blk - 1088) * 4 + w;     // l*512 + e
        int l = gw >> 9;
        int e = gw & (D - 1);
        const float* base = links + (size_t)l * D * D + e;
        float v[8];
#pragma unroll
        for (int i = 0; i < 8; ++i) v[i] = base[(size_t)(i * 64 + lane) * D];
        float mv[3]; int mi[3];
        for (int k = 0; k < 3; ++k) {
            float lm = -1.f; int li = 0x7fffffff;
#pragma unroll
            for (int i = 0; i < 8; ++i)
                if (v[i] > lm) { lm = v[i]; li = i * 64 + lane; }
#pragma unroll
            for (int off = 32; off; off >>= 1) {
                float ov = __shfl_xor(lm, off);
                int oi = __shfl_xor(li, off);
                if (ov > lm || (ov == lm && oi < li)) { lm = ov; li = oi; }
            }
            mv[k] = lm; mi[k] = li;
            if (li < D && (li & 63) == lane) v[li >> 6] = -1.f;
        }
        if (lane == 0) {
            float invs = 1.f / (mv[0] + mv[1] + mv[2] + 1e-8f);
            uint_t f0 = (uint_t)mi[0] ^ (((uint_t)mi[0] >> 3) & 7u);
            uint_t f1 = (uint_t)mi[1] ^ (((uint_t)mi[1] >> 3) & 7u);
            uint_t f2m = (uint_t)mi[2] ^ (((uint_t)mi[2] >> 3) & 7u);
            pidx[gw] = f0 | (f1 << 9) | (f2m << 18);
            wval[(l * 3 + 0) * D + e] = mv[0] * invs;
            wval[(l * 3 + 1) * D + e] = mv[1] * invs;
            wval[(l * 3 + 2) * D + e] = mv[2] * invs;
        }
    }
}

// ---- fused rectify blend for one e-half, one nn-pair (packed over nn)
__device__ __forceinline__ f2 blend(f2 gA, f2 gB, f2 gC, f2 w0, f2 w1, f2 w2,
                                    f2 acn, f2 btn, f2 cc, f2 rr, f2 aa, f2 one2) {
    f2 gs = vfma(w0, gA, vfma(w1, gB, w2 * gC));
    f2 t  = vfma(acn, cc, btn);
    f2 E; E.x = __builtin_amdgcn_exp2f(t.x); E.y = __builtin_amdgcn_exp2f(t.y);
    f2 A  = E + one2;
    f2 P; P.x = __builtin_amdgcn_rcpf(A.x); P.y = __builtin_amdgcn_rcpf(A.y);
    f2 d  = aa - rr;
    f2 q  = one2 - P;
    f2 nd = d * d;
    return vfma(gs, q, P * nd);            // gs*(1-P) + P*node
}

// ================= fused main kernel =================
__global__ __launch_bounds__(256, 4) void avsl_main_kernel(
    const float* __restrict__ n1,      // (3,B1,D) f32 normalized emb1
    const ushort_t* __restrict__ n2h,  // (3,B2,D) bf16 normalized emb2
    const float* __restrict__ cert1,   // (3,B1,D) f32
    const ushort_t* __restrict__ c2h,  // (2,B2,D) bf16 cert2 layers 1,2
    const uint_t* __restrict__ pidx,   // (2,D) phi-swizzled packed top-3 indices
    const float* __restrict__ wval,    // (2,3,D) normalized weights
    const float* __restrict__ alpha,   // (2,D)
    const float* __restrict__ beta,    // (2,D)
    float* __restrict__ out)           // (B1,B2)
{
    __shared__ F4 vbuf[3 * D];         // v0 ping / v0 pong / v1
    __shared__ float pbuf[16];
    const int tid  = threadIdx.x;
    const int lane = tid & 63;
    const int wid  = tid >> 6;
    const int b    = blockIdx.x >> 4;
    const int n0   = (blockIdx.x & 15) * 32;
    const int e0   = wid * 128 + lane * 2;     // lane owns e0, e0+1

    // ---- persistent per-e tables (scalars duplicated into f2 halves for pk ops)
    float2 a0  = *(const float2*)(n1 + (size_t)(0 * NB1 + b) * D + e0);
    float2 a1  = *(const float2*)(n1 + (size_t)(1 * NB1 + b) * D + e0);
    float2 a2  = *(const float2*)(n1 + (size_t)(2 * NB1 + b) * D + e0);
    float2 al1 = *(const float2*)(alpha + e0);
    float2 al2 = *(const float2*)(alpha + D + e0);
    float2 c11 = *(const float2*)(cert1 + (size_t)(1 * NB1 + b) * D + e0);
    float2 c12 = *(const float2*)(cert1 + (size_t)(2 * NB1 + b) * D + e0);
    float2 be1 = *(const float2*)(beta + e0);
    float2 be2 = *(const float2*)(beta + D + e0);

    const f2 one2 = { 1.f, 1.f };
    f2 a0xx = { a0.x, a0.x }, a0yy = { a0.y, a0.y };
    f2 a1xx = { a1.x, a1.x }, a1yy = { a1.y, a1.y };
    f2 a2xx = { a2.x, a2.x }, a2yy = { a2.y, a2.y };
    f2 acn1xx = { -al1.x * c11.x * LOG2E, -al1.x * c11.x * LOG2E };
    f2 acn1yy = { -al1.y * c11.y * LOG2E, -al1.y * c11.y * LOG2E };
    f2 acn2xx = { -al2.x * c12.x * LOG2E, -al2.x * c12.x * LOG2E };
    f2 acn2yy = { -al2.y * c12.y * LOG2E, -al2.y * c12.y * LOG2E };
    f2 btn1xx = { -be1.x * LOG2E, -be1.x * LOG2E };
    f2 btn1yy = { -be1.y * LOG2E, -be1.y * LOG2E };
    f2 btn2xx = { -be2.x * LOG2E, -be2.x * LOG2E };
    f2 btn2yy = { -be2.y * LOG2E, -be2.y * LOG2E };

    f2 w1x[3], w1y[3], w2x[3], w2y[3];
#pragma unroll
    for (int k = 0; k < 3; ++k) {
        float2 t1 = *(const float2*)(wval + k * D + e0);
        float2 t2 = *(const float2*)(wval + (3 + k) * D + e0);
        w1x[k].x = t1.x; w1x[k].y = t1.x;
        w1y[k].x = t1.y; w1y[k].y = t1.y;
        w2x[k].x = t2.x; w2x[k].y = t2.x;
        w2y[k].x = t2.y; w2y[k].y = t2.y;
    }
    uint2 p1 = *(const uint2*)(pidx + e0);
    uint2 p2 = *(const uint2*)(pidx + D + e0);

    // hoisted LDS gather pointers (parity handled via [512] imm offset)
    const F4* q1a0 = &vbuf[p1.x & 511u];
    const F4* q1b0 = &vbuf[(p1.x >> 9) & 511u];
    const F4* q1c0 = &vbuf[(p1.x >> 18) & 511u];
    const F4* q1a1 = &vbuf[p1.y & 511u];
    const F4* q1b1 = &vbuf[(p1.y >> 9) & 511u];
    const F4* q1c1 = &vbuf[(p1.y >> 18) & 511u];
    const F4* q2a0 = &vbuf[1024 + (p2.x & 511u)];
    const F4* q2b0 = &vbuf[1024 + ((p2.x >> 9) & 511u)];
    const F4* q2c0 = &vbuf[1024 + ((p2.x >> 18) & 511u)];
    const F4* q2a1 = &vbuf[1024 + (p2.y & 511u)];
    const F4* q2b1 = &vbuf[1024 + ((p2.y >> 9) & 511u)];
    const F4* q2c1 = &vbuf[1024 + ((p2.y >> 18) & 511u)];
    const int sl0 = e0 ^ ((e0 >> 3) & 7);
    const int sl1 = (e0 + 1) ^ (((e0 + 1) >> 3) & 7);
    F4* qw0a = &vbuf[sl0];
    F4* qw0b = &vbuf[sl1];
    F4* qw1a = &vbuf[1024 + sl0];
    F4* qw1b = &vbuf[1024 + sl1];

    // stream pointers (advanced 4 rows per group)
    const ushort_t* pr0 = n2h + (size_t)(0 * NB2 + n0) * D + e0;
    const ushort_t* pr1 = n2h + (size_t)(1 * NB2 + n0) * D + e0;
    const ushort_t* pr2 = n2h + (size_t)(2 * NB2 + n0) * D + e0;
    const ushort_t* pc1 = c2h + (size_t)(0 * NB2 + n0) * D + e0;
    const ushort_t* pc2 = c2h + (size_t)(1 * NB2 + n0) * D + e0;

    // ---- prologue: loads for g=0, L0(0) -> v0[ping]
    uint_t r1c[4], c1c[4], r0c[4];
#pragma unroll
    for (int nn = 0; nn < 4; ++nn) {
        r0c[nn] = *(const uint_t*)(pr0 + nn * D);
        r1c[nn] = *(const uint_t*)(pr1 + nn * D);
        c1c[nn] = *(const uint_t*)(pc1 + nn * D);
    }
    {
        F4 v0a, v0b; f2 d;
        d = a0xx - unplo(r0c[0], r0c[1]); v0a.lo = d * d;
        d = a0xx - unplo(r0c[2], r0c[3]); v0a.hi = d * d;
        d = a0yy - unphi(r0c[0], r0c[1]); v0b.lo = d * d;
        d = a0yy - unphi(r0c[2], r0c[3]); v0b.hi = d * d;
        qw0a[0] = v0a;
        qw0b[0] = v0b;
    }
    __syncthreads();

#pragma unroll 2
    for (int g = 0; g < 8; ++g) {
        // ================= phase A =================
        if (g) {
            if (tid < 4)
                out[(size_t)b * NB2 + n0 + (g - 1) * 4 + tid] =
                    pbuf[tid] + pbuf[4 + tid] + pbuf[8 + tid] + pbuf[12 + tid];
        }
        uint_t r0n[4], r2c[4], c2c[4];
#pragma unroll
        for (int nn = 0; nn < 4; ++nn) {
            r0n[nn] = *(const uint_t*)(pr0 + (4 + nn) * D);
            r2c[nn] = *(const uint_t*)(pr2 + nn * D);
            c2c[nn] = *(const uint_t*)(pc2 + nn * D);
        }
        // L1: gather v0[g&1], blend, write v1
        {
            F4 gA0 = q1a0[(g & 1) * 512], gB0 = q1b0[(g & 1) * 512], gC0 = q1c0[(g & 1) * 512];
            F4 gA1 = q1a1[(g & 1) * 512], gB1 = q1b1[(g & 1) * 512], gC1 = q1c1[(g & 1) * 512];
            f2 r1xa = unplo(r1c[0], r1c[1]), r1xb = unplo(r1c[2], r1c[3]);
            f2 r1ya = unphi(r1c[0], r1c[1]), r1yb = unphi(r1c[2], r1c[3]);
            f2 c1xa = unplo(c1c[0], c1c[1]), c1xb = unplo(c1c[2], c1c[3]);
            f2 c1ya = unphi(c1c[0], c1c[1]), c1yb = unphi(c1c[2], c1c[3]);
            F4 o0, o1;
            o0.lo = blend(gA0.lo, gB0.lo, gC0.lo, w1x[0], w1x[1], w1x[2],
                          acn1xx, btn1xx, c1xa, r1xa, a1xx, one2);
            o0.hi = blend(gA0.hi, gB0.hi, gC0.hi, w1x[0], w1x[1], w1x[2],
                          acn1xx, btn1xx, c1xb, r1xb, a1xx, one2);
            o1.lo = blend(gA1.lo, gB1.lo, gC1.lo, w1y[0], w1y[1], w1y[2],
                          acn1yy, btn1yy, c1ya, r1ya, a1yy, one2);
            o1.hi = blend(gA1.hi, gB1.hi, gC1.hi, w1y[0], w1y[1], w1y[2],
                          acn1yy, btn1yy, c1yb, r1yb, a1yy, one2);
            qw1a[0] = o0;
            qw1b[0] = o1;
        }
        __syncthreads();

        // ================= phase B =================
        uint_t r1n[4], c1n[4];
#pragma unroll
        for (int nn = 0; nn < 4; ++nn) {
            r1n[nn] = *(const uint_t*)(pr1 + (4 + nn) * D);
            c1n[nn] = *(const uint_t*)(pc1 + (4 + nn) * D);
        }
        // L2: gather v1, blend, accumulate
        f2 acc_a, acc_b;
        {
            F4 gA0 = q2a0[0], gB0 = q2b0[0], gC0 = q2c0[0];
            F4 gA1 = q2a1[0], gB1 = q2b1[0], gC1 = q2c1[0];
            f2 r2xa = unplo(r2c[0], r2c[1]), r2xb = unplo(r2c[2], r2c[3]);
            f2 r2ya = unphi(r2c[0], r2c[1]), r2yb = unphi(r2c[2], r2c[3]);
            f2 c2xa = unplo(c2c[0], c2c[1]), c2xb = unplo(c2c[2], c2c[3]);
            f2 c2ya = unphi(c2c[0], c2c[1]), c2yb = unphi(c2c[2], c2c[3]);
            acc_a = blend(gA0.lo, gB0.lo, gC0.lo, w2x[0], w2x[1], w2x[2],
                          acn2xx, btn2xx, c2xa, r2xa, a2xx, one2);
            acc_b = blend(gA0.hi, gB0.hi, gC0.hi, w2x[0], w2x[1], w2x[2],
                          acn2xx, btn2xx, c2xb, r2xb, a2xx, one2);
            acc_a = acc_a + blend(gA1.lo, gB1.lo, gC1.lo, w2y[0], w2y[1], w2y[2],
                                  acn2yy, btn2yy, c2ya, r2ya, a2yy, one2);
            acc_b = acc_b + blend(gA1.hi, gB1.hi, gC1.hi, w2y[0], w2y[1], w2y[2],
                                  acn2yy, btn2yy, c2yb, r2yb, a2yy, one2);
        }
        // L0 for g+1 -> v0[(g+1)&1]
        {
            F4 v0a, v0b; f2 d;
            d = a0xx - unplo(r0n[0], r0n[1]); v0a.lo = d * d;
            d = a0xx - unplo(r0n[2], r0n[3]); v0a.hi = d * d;
            d = a0yy - unphi(r0n[0], r0n[1]); v0b.lo = d * d;
            d = a0yy - unphi(r0n[2], r0n[3]); v0b.hi = d * d;
            qw0a[((g + 1) & 1) * 512] = v0a;
            qw0b[((g + 1) & 1) * 512] = v0b;
        }
        // wave reduction: DPP split butterfly (VALU) + xor16 swizzle + xor32
        {
            float c0 = acc_a.x, c1 = acc_a.y, c2 = acc_b.x, c3 = acc_b.y;
            float pA = DPPF(c0, 0xB1);   // quad_perm [1,0,3,2]  (xor 1)
            float pB = DPPF(c1, 0xB1);
            float pC = DPPF(c2, 0xB1);
            float pD = DPPF(c3, 0xB1);
            float u0, u1;
            if (lane & 1) { u0 = c1 + pB; u1 = c3 + pD; }
            else          { u0 = c0 + pA; u1 = c2 + pC; }
            float q0 = DPPF(u0, 0x4E);   // quad_perm [2,3,0,1]  (xor 2)
            float q1 = DPPF(u1, 0x4E);
            float v = (lane & 2) ? (u1 + q1) : (u0 + q0);   // holds nn = lane&3
            v += DPPF(v, 0x124);          // row_ror:4
            v += DPPF(v, 0x128);          // row_ror:8
            v += __int_as_float(__builtin_amdgcn_ds_swizzle(__float_as_int(v), 0x401F)); // xor 16
            v += __shfl_xor(v, 32);
            if (lane < 4) pbuf[wid * 4 + lane] = v;
        }
        __syncthreads();

#pragma unroll
        for (int nn = 0; nn < 4; ++nn) { r1c[nn] = r1n[nn]; c1c[nn] = c1n[nn]; }
        pr0 += 4 * D; pr1 += 4 * D; pr2 += 4 * D; pc1 += 4 * D; pc2 += 4 * D;
    }

    // epilogue: out-write for g=7
    if (tid < 4)
        out[(size_t)b * NB2 + n0 + 28 + tid] =
            pbuf[tid] + pbuf[4 + tid] + pbuf[8 + tid] + pbuf[12 + tid];
}

extern "C" void kernel_launch(void* const* d_in, const int* in_sizes, int n_in,
                              void* d_out, int out_size, void* d_ws, size_t ws_size,
                              hipStream_t stream) {
    const float* emb1  = (const float*)d_in[0];  // (3,256,512)
    const float* cert1 = (const float*)d_in[1];  // (3,256,512)
    const float* emb2  = (const float*)d_in[2];  // (3,512,512)
    const float* cert2 = (const float*)d_in[3];  // (3,512,512)
    const float* links = (const float*)d_in[4];  // (2,512,512)
    const float* alpha = (const float*)d_in[5];  // (2,512)
    const float* beta  = (const float*)d_in[6];  // (2,512)
    float* out = (float*)d_out;                  // (256,512)

    float* n1      = (float*)d_ws;                      // 3*256*512 f32
    ushort_t* n2h  = (ushort_t*)(n1 + 3 * NB1 * D);     // 3*512*512 bf16
    ushort_t* c2h  = n2h + 3 * NB2 * D;                 // 2*512*512 bf16
    uint_t* pidx   = (uint_t*)(c2h + 2 * NB2 * D);      // 2*512 u32
    float* wval    = (float*)(pidx + 2 * D);            // 2*3*512 f32

    hipLaunchKernelGGL(prep_kernel, dim3(1344), dim3(256), 0, stream,
                       emb1, emb2, cert2, links, n1, n2h, c2h, pidx, wval);
    hipLaunchKernelGGL(avsl_main_kernel, dim3(4096), dim3(256), 0, stream,
                       n1, n2h, cert1, c2h, pidx, wval, alpha, beta, out);
}